// Round 7
// baseline (255.691 us; speedup 1.0000x reference)
//
#include <hip/hip_runtime.h>
#include <hip/hip_cooperative_groups.h>
#include <cstdint>
#include <climits>

#pragma clang fp contract(off)

namespace cg = cooperative_groups;

#define NCAM 6
#define NCLS 10
#define NKEY 60          // cam*10+cls
#define IMGW 1600
#define IMGH 900
#define GRID 512         // 2 blocks/CU guaranteed via __launch_bounds__(256,2)

// XLA-style float->int32: saturate out-of-range, NaN -> 0. (Verified R3..R6.)
__device__ __forceinline__ int sat_f2i(float f) {
    if (f != f) return 0;
    if (f >= 2147483648.0f) return INT_MAX;
    if (f <= -2147483648.0f) return INT_MIN;
    return (int)f;
}

// Single cooperative kernel:
//  Phase A: units [0,PB) project 256 boxes each -> projW[36][N];
//           units [PB,PB+60) bucket dets of key k into per-wave sub-slabs.
//  Phase B: units bx*k over (PB x 60): 256 boxes vs bucket k, wave-uniform
//           det stream (scalar loads), deterministic partial[k][box] store.
//  Phase C: units [0,PB): reduce 60 partials, argmax, write out.
__global__ __launch_bounds__(256, 2) void fused_coop(
        const float*  __restrict__ boxes,   // [N][7]
        const float*  __restrict__ ia,      // [6][4][4]
        const float*  __restrict__ la,      // [4][4]
        const float*  __restrict__ l2i,     // [6][4][4]
        const float4* __restrict__ det_boxes,
        const int*    __restrict__ det_labels,
        const float*  __restrict__ det_scores,
        const int*    __restrict__ det_batch,
        const int*    __restrict__ det_cam,
        float* __restrict__ projW,          // [36][N]
        float* __restrict__ slab,           // [60*4][CAPW][8]
        int*   __restrict__ cnt,            // [60*4]
        float* __restrict__ partial,        // [60][N]
        float* __restrict__ out,            // [2*N]
        int N, int M, int PB, int CAPW) {
    cg::grid_group gg = cg::this_grid();
    int tid = threadIdx.x;

    // ---------------- Phase A ----------------
    for (int u = blockIdx.x; u < PB + NKEY; u += GRID) {
        if (u < PB) {
            // projection (validated R3..R6 math)
            int n = u * 256 + tid;
            if (n >= N) continue;
            float bx = boxes[n*7+0], by = boxes[n*7+1], bz = boxes[n*7+2];
            float dx = boxes[n*7+3], dy = boxes[n*7+4], dz = boxes[n*7+5];
            float yaw = boxes[n*7+6];
            float c = (float)cos((double)yaw);
            float s = (float)sin((double)yaw);

            float a00=la[0],a01=la[1],a02=la[2],t0=la[3];
            float a10=la[4],a11=la[5],a12=la[6],t1=la[7];
            float a20=la[8],a21=la[9],a22=la[10],t2=la[11];
            float det = a00*(a11*a22-a12*a21) - a01*(a10*a22-a12*a20) + a02*(a10*a21-a11*a20);
            float id = 1.0f/det;
            float r00=(a11*a22-a12*a21)*id, r01=(a02*a21-a01*a22)*id, r02=(a01*a12-a02*a11)*id;
            float r10=(a12*a20-a10*a22)*id, r11=(a00*a22-a02*a20)*id, r12=(a02*a10-a00*a12)*id;
            float r20=(a10*a21-a11*a20)*id, r21=(a01*a20-a00*a21)*id, r22=(a00*a11-a01*a10)*id;

            float PX[8], PY[8], PZ[8];
            #pragma unroll
            for (int k = 0; k < 8; k++) {
                float sx = ((k==0||k==1||k==4||k==5) ?  0.5f : -0.5f) * dx;
                float sy = ((k==0||k==3||k==4||k==7) ?  0.5f : -0.5f) * dy;
                float sz = ((k>=4)                   ?  0.5f : -0.5f) * dz;
                float cx = sx*c - sy*s + bx;
                float cy = sx*s + sy*c + by;
                float cz = sz + bz;
                float ux = cx - t0, uy = cy - t1, uz = cz - t2;
                PX[k] = r00*ux + r01*uy + r02*uz;
                PY[k] = r10*ux + r11*uy + r12*uz;
                PZ[k] = r20*ux + r21*uy + r22*uz;
            }
            for (int cam = 0; cam < NCAM; cam++) {
                const float* L = l2i + cam*16;
                const float* A = ia  + cam*16;
                int minx = INT_MAX, miny = INT_MAX, maxx = INT_MIN, maxy = INT_MIN;
                #pragma unroll
                for (int k = 0; k < 8; k++) {
                    float u3 = L[0]*PX[k] + L[1]*PY[k] + L[2]*PZ[k]  + L[3];
                    float v3 = L[4]*PX[k] + L[5]*PY[k] + L[6]*PZ[k]  + L[7];
                    float w3 = L[8]*PX[k] + L[9]*PY[k] + L[10]*PZ[k] + L[11];
                    float zc = fminf(fmaxf(w3, 1e-5f), 100000.0f);
                    float x = u3 / zc, y = v3 / zc;
                    float xx = A[0]*x + A[1]*y + A[2]*zc + A[3];
                    float yy = A[4]*x + A[5]*y + A[6]*zc + A[7];
                    int pxi = sat_f2i(xx); pxi = min(max(pxi, 0), IMGW);
                    int pyi = sat_f2i(yy); pyi = min(max(pyi, 0), IMGH);
                    minx = min(minx, pxi); maxx = max(maxx, pxi);
                    miny = min(miny, pyi); maxy = max(maxy, pyi);
                }
                float x1 = (float)minx, y1 = (float)miny, x2 = (float)maxx, y2 = (float)maxy;
                float validf = ((x2 - x1) > 0.0f && (y2 - y1) > 0.0f) ? 1.0f : 0.0f;
                projW[(cam*6+0)*N + n] = x1;
                projW[(cam*6+1)*N + n] = y1;
                projW[(cam*6+2)*N + n] = x2;
                projW[(cam*6+3)*N + n] = y2;
                projW[(cam*6+4)*N + n] = (x2 - x1) * (y2 - y1);
                projW[(cam*6+5)*N + n] = validf;
            }
        } else {
            // bucketing key k: 4 waves, independent ranges, ballot compaction
            int k = u - PB;
            int cam = k / NCLS, cls = k % NCLS;
            int w = tid >> 6, lane = tid & 63;
            int per = (M + 3) >> 2;
            int m0 = w * per, m1 = min(m0 + per, M);
            float* sb = slab + (size_t)(k * 4 + w) * CAPW * 8;
            int pos = 0;
            for (int c = m0; c < m1; c += 64) {
                int m = c + lane;
                bool pred = false;
                if (m < m1) {
                    int dc = det_cam[m], db = det_batch[m], dl = det_labels[m] - 1;
                    pred = (db == 0) && (dc == cam) && (dl == cls);
                }
                unsigned long long ball = __ballot(pred);
                if (pred) {
                    int p = pos + __popcll(ball & ((1ull << lane) - 1ull));
                    float4 b = det_boxes[m];
                    float area = (b.z - b.x) * (b.w - b.y);
                    float4* o = (float4*)(sb + (size_t)p * 8);
                    o[0] = b;
                    o[1] = make_float4(area, det_scores[m], 0.0f, 0.0f);
                }
                pos += __popcll(ball);
            }
            if (lane == 0) cnt[k * 4 + w] = pos;
        }
    }

    gg.sync();

    // ---------------- Phase B ----------------
    for (int u = blockIdx.x; u < PB * NKEY; u += GRID) {
        int k = u / PB;
        int bx = u - k * PB;
        int cam = k / NCLS;
        int box = bx * 256 + tid;
        int bidx = min(box, N - 1);

        float Px1 = projW[(cam*6+0)*N + bidx];
        float Py1 = projW[(cam*6+1)*N + bidx];
        float Px2 = projW[(cam*6+2)*N + bidx];
        float Py2 = projW[(cam*6+3)*N + bidx];
        float Pa  = projW[(cam*6+4)*N + bidx];
        float Pv  = projW[(cam*6+5)*N + bidx];

        float acc = 0.0f;
        #pragma unroll
        for (int sub = 0; sub < 4; sub++) {
            int nk = cnt[k * 4 + sub];
            const float4* bp = (const float4*)(slab + (size_t)(k * 4 + sub) * CAPW * 8);
            for (int m = 0; m < nk; m++) {
                float4 b = bp[2*m];
                float4 q = bp[2*m+1];
                float ltx = fmaxf(b.x, Px1);
                float lty = fmaxf(b.y, Py1);
                float rbx = fminf(b.z, Px2);
                float rby = fminf(b.w, Py2);
                float iw = fmaxf(rbx - ltx, 0.0f);
                float ih = fmaxf(rby - lty, 0.0f);
                float inter = iw * ih;
                float uni = (q.x + Pa) - inter;
                float r = __fdividef(inter, uni);
                float iou = (uni > 0.0f) ? r : 0.0f;
                acc += iou * q.y;
            }
        }
        if (box < N) partial[(size_t)k * N + box] = acc * Pv;
    }

    gg.sync();

    // ---------------- Phase C ----------------
    for (int u = blockIdx.x; u < PB; u += GRID) {
        int n = u * 256 + tid;
        if (n >= N) continue;
        float p[NCLS];
        #pragma unroll
        for (int c = 0; c < NCLS; c++) p[c] = 0.0f;
        #pragma unroll
        for (int cam = 0; cam < NCAM; cam++)
            #pragma unroll
            for (int c = 0; c < NCLS; c++)
                p[c] += partial[(size_t)(cam * NCLS + c) * N + n];
        float nv = 0.0f;
        #pragma unroll
        for (int cam = 0; cam < NCAM; cam++) nv += projW[(cam*6+5)*N + n];
        float denom = 1e-5f + nv;
        float best = -1e30f; int bk = 0;
        #pragma unroll
        for (int c = 0; c < NCLS; c++) {
            float v = p[c] / denom;
            if (v > best) { best = v; bk = c; }   // strict >: first-max (jnp.argmax)
        }
        out[n]     = (float)(bk + 1);
        out[N + n] = best;
    }
}

extern "C" void kernel_launch(void* const* d_in, const int* in_sizes, int n_in,
                              void* d_out, int out_size, void* d_ws, size_t ws_size,
                              hipStream_t stream) {
    const float*  pred_boxes = (const float*)d_in[0];
    const float*  ia         = (const float*)d_in[1];
    const float*  la         = (const float*)d_in[2];
    const float*  l2i        = (const float*)d_in[3];
    const float4* det_boxes  = (const float4*)d_in[4];
    const int*    det_labels = (const int*)d_in[5];
    const float*  det_scores = (const float*)d_in[6];
    const int*    det_batch  = (const int*)d_in[7];
    const int*    det_cam    = (const int*)d_in[8];
    float* out = (float*)d_out;

    int N = in_sizes[0] / 7;   // 4096
    int M = in_sizes[4] / 4;   // 6144
    int PB = (N + 255) / 256;  // 16
    int CAPW = (M + 3) / 4;    // worst-case per-wave bucket size

    // ws layout (16B-aligned slabs)
    char* w = (char*)d_ws;
    float* slab    = (float*)w;                               // 240*CAPW*8 floats
    size_t off = (size_t)NKEY * 4 * CAPW * 8 * 4;
    float* projW   = (float*)(w + off);                       // 36*N floats
    off += (size_t)36 * N * 4;
    float* partial = (float*)(w + off);                       // 60*N floats
    off += (size_t)NKEY * N * 4;
    int*   cnt     = (int*)(w + off);                         // 240 ints

    void* args[] = {
        (void*)&pred_boxes, (void*)&ia, (void*)&la, (void*)&l2i,
        (void*)&det_boxes, (void*)&det_labels, (void*)&det_scores,
        (void*)&det_batch, (void*)&det_cam,
        (void*)&projW, (void*)&slab, (void*)&cnt, (void*)&partial,
        (void*)&out, (void*)&N, (void*)&M, (void*)&PB, (void*)&CAPW
    };
    hipLaunchCooperativeKernel((const void*)fused_coop, dim3(GRID), dim3(256),
                               args, 0, stream);
}

// Round 8
// 119.943 us; speedup vs baseline: 2.1318x; 2.1318x over previous
//
#include <hip/hip_runtime.h>
#include <cstdint>
#include <climits>

#pragma clang fp contract(off)

#define NCAM 6
#define NCLS 10
#define NKEY 60          // cam*10+cls
#define IMGW 1600
#define IMGH 900
#define TBOX 4           // boxes per thread in main kernel
#define CHUNK 512        // dets staged per LDS pass

// XLA-style float->int32: saturate out-of-range, NaN -> 0. (Verified R3..R7.)
__device__ __forceinline__ int sat_f2i(float f) {
    if (f != f) return 0;
    if (f >= 2147483648.0f) return INT_MAX;
    if (f <= -2147483648.0f) return INT_MIN;
    return (int)f;
}

// ---------------- K1: prep = projection (blocks 0..PB-1) + bucketing -------
// (unchanged from R6 — validated, not a bottleneck)
__global__ __launch_bounds__(256) void prep_kernel(
        const float*  __restrict__ boxes,   // [N][7]
        const float*  __restrict__ ia,      // [6][4][4]
        const float*  __restrict__ la,      // [4][4]
        const float*  __restrict__ l2i,     // [6][4][4]
        const float4* __restrict__ det_boxes,
        const int*    __restrict__ det_labels,
        const float*  __restrict__ det_scores,
        const int*    __restrict__ det_batch,
        const int*    __restrict__ det_cam,
        float* __restrict__ projW,          // [36][N] comp-major
        float* __restrict__ slab,           // [60*4][CAPW][8]
        int*   __restrict__ cnt,            // [60*4]
        int N, int M, int PB, int CAPW) {
    int tid = threadIdx.x;

    if ((int)blockIdx.x < PB) {
        int n = blockIdx.x * 256 + tid;
        if (n >= N) return;
        float bx = boxes[n*7+0], by = boxes[n*7+1], bz = boxes[n*7+2];
        float dx = boxes[n*7+3], dy = boxes[n*7+4], dz = boxes[n*7+5];
        float yaw = boxes[n*7+6];
        float c = (float)cos((double)yaw);
        float s = (float)sin((double)yaw);

        float a00=la[0],a01=la[1],a02=la[2],t0=la[3];
        float a10=la[4],a11=la[5],a12=la[6],t1=la[7];
        float a20=la[8],a21=la[9],a22=la[10],t2=la[11];
        float det = a00*(a11*a22-a12*a21) - a01*(a10*a22-a12*a20) + a02*(a10*a21-a11*a20);
        float id = 1.0f/det;
        float r00=(a11*a22-a12*a21)*id, r01=(a02*a21-a01*a22)*id, r02=(a01*a12-a02*a11)*id;
        float r10=(a12*a20-a10*a22)*id, r11=(a00*a22-a02*a20)*id, r12=(a02*a10-a00*a12)*id;
        float r20=(a10*a21-a11*a20)*id, r21=(a01*a20-a00*a21)*id, r22=(a00*a11-a01*a10)*id;

        float PX[8], PY[8], PZ[8];
        #pragma unroll
        for (int k = 0; k < 8; k++) {
            float sx = ((k==0||k==1||k==4||k==5) ?  0.5f : -0.5f) * dx;
            float sy = ((k==0||k==3||k==4||k==7) ?  0.5f : -0.5f) * dy;
            float sz = ((k>=4)                   ?  0.5f : -0.5f) * dz;
            float cx = sx*c - sy*s + bx;
            float cy = sx*s + sy*c + by;
            float cz = sz + bz;
            float ux = cx - t0, uy = cy - t1, uz = cz - t2;
            PX[k] = r00*ux + r01*uy + r02*uz;
            PY[k] = r10*ux + r11*uy + r12*uz;
            PZ[k] = r20*ux + r21*uy + r22*uz;
        }
        for (int cam = 0; cam < NCAM; cam++) {
            const float* L = l2i + cam*16;
            const float* A = ia  + cam*16;
            int minx = INT_MAX, miny = INT_MAX, maxx = INT_MIN, maxy = INT_MIN;
            #pragma unroll
            for (int k = 0; k < 8; k++) {
                float u = L[0]*PX[k] + L[1]*PY[k] + L[2]*PZ[k]  + L[3];
                float v = L[4]*PX[k] + L[5]*PY[k] + L[6]*PZ[k]  + L[7];
                float w = L[8]*PX[k] + L[9]*PY[k] + L[10]*PZ[k] + L[11];
                float zc = fminf(fmaxf(w, 1e-5f), 100000.0f);
                float x = u / zc, y = v / zc;
                float xx = A[0]*x + A[1]*y + A[2]*zc + A[3];
                float yy = A[4]*x + A[5]*y + A[6]*zc + A[7];
                int pxi = sat_f2i(xx); pxi = min(max(pxi, 0), IMGW);
                int pyi = sat_f2i(yy); pyi = min(max(pyi, 0), IMGH);
                minx = min(minx, pxi); maxx = max(maxx, pxi);
                miny = min(miny, pyi); maxy = max(maxy, pyi);
            }
            float x1 = (float)minx, y1 = (float)miny, x2 = (float)maxx, y2 = (float)maxy;
            float validf = ((x2 - x1) > 0.0f && (y2 - y1) > 0.0f) ? 1.0f : 0.0f;
            projW[(cam*6+0)*N + n] = x1;
            projW[(cam*6+1)*N + n] = y1;
            projW[(cam*6+2)*N + n] = x2;
            projW[(cam*6+3)*N + n] = y2;
            projW[(cam*6+4)*N + n] = (x2 - x1) * (y2 - y1);
            projW[(cam*6+5)*N + n] = validf;
        }
        return;
    }

    // bucketing key k: 4 waves, independent det ranges, ballot compaction
    int k = (int)blockIdx.x - PB;
    int cam = k / NCLS, cls = k % NCLS;
    int w = tid >> 6, lane = tid & 63;
    int per = (M + 3) >> 2;
    int m0 = w * per, m1 = min(m0 + per, M);
    float* base = slab + (size_t)(k * 4 + w) * CAPW * 8;
    int pos = 0;
    for (int c = m0; c < m1; c += 64) {
        int m = c + lane;
        bool pred = false;
        if (m < m1) {
            int dc = det_cam[m], db = det_batch[m], dl = det_labels[m] - 1;
            pred = (db == 0) && (dc == cam) && (dl == cls);
        }
        unsigned long long ball = __ballot(pred);
        if (pred) {
            int p = pos + __popcll(ball & ((1ull << lane) - 1ull));
            float4 b = det_boxes[m];
            float area = (b.z - b.x) * (b.w - b.y);
            float4* o = (float4*)(base + (size_t)p * 8);
            o[0] = b;
            o[1] = make_float4(area, det_scores[m], 0.0f, 0.0f);
        }
        pos += __popcll(ball);
    }
    if (lane == 0) cnt[k * 4 + w] = pos;
}

// ---------------- K2: main accumulation ------------------------------------
// grid (ceil(N/1024), 60). Block = 1024 boxes (4/thread, stride-256) x key k.
// Bucket dets staged chunk-wise into LDS (coalesced), then broadcast-read
// (same-address -> conflict-free) while each thread does 4 IoUs per det.
__global__ __launch_bounds__(256) void main_kernel(
        const float* __restrict__ projW,
        const float* __restrict__ slab,
        const int*   __restrict__ cnt,
        float*       __restrict__ partial,   // [60][N]
        int N, int CAPW) {
    #pragma clang fp contract(fast)          // IoU loop may fuse (thr 0.2, safe)
    int tid = threadIdx.x;
    int k = blockIdx.y;
    int cam = k / NCLS;
    int box0 = blockIdx.x * (256 * TBOX) + tid;

    __shared__ float4 sbox[CHUNK];
    __shared__ float2 sq[CHUNK];

    float Px1[TBOX], Py1[TBOX], Px2[TBOX], Py2[TBOX], Pa[TBOX], Pv[TBOX], acc[TBOX];
    #pragma unroll
    for (int t = 0; t < TBOX; t++) {
        int b = box0 + t * 256;
        int bi = min(b, N - 1);              // loads valid; store guarded
        Px1[t] = projW[(cam*6+0)*N + bi];
        Py1[t] = projW[(cam*6+1)*N + bi];
        Px2[t] = projW[(cam*6+2)*N + bi];
        Py2[t] = projW[(cam*6+3)*N + bi];
        Pa[t]  = projW[(cam*6+4)*N + bi];
        Pv[t]  = projW[(cam*6+5)*N + bi];
        acc[t] = 0.0f;
    }

    #pragma unroll
    for (int sub = 0; sub < 4; sub++) {
        int nk = cnt[k * 4 + sub];           // block-uniform
        const float4* gb = (const float4*)(slab + (size_t)(k * 4 + sub) * CAPW * 8);
        for (int base = 0; base < nk; base += CHUNK) {
            int cc = min(CHUNK, nk - base);
            __syncthreads();
            for (int i = tid; i < cc; i += 256) {
                float4 b0 = gb[(size_t)(base + i) * 2];
                float4 b1 = gb[(size_t)(base + i) * 2 + 1];
                sbox[i] = b0;
                sq[i] = make_float2(b1.x, b1.y);
            }
            __syncthreads();
            for (int m = 0; m < cc; m++) {
                float4 b = sbox[m];
                float2 q = sq[m];
                #pragma unroll
                for (int t = 0; t < TBOX; t++) {
                    float ltx = fmaxf(b.x, Px1[t]);
                    float lty = fmaxf(b.y, Py1[t]);
                    float rbx = fminf(b.z, Px2[t]);
                    float rby = fminf(b.w, Py2[t]);
                    float iw = fmaxf(rbx - ltx, 0.0f);
                    float ih = fmaxf(rby - lty, 0.0f);
                    float inter = iw * ih;
                    float uni = (q.x + Pa[t]) - inter;
                    float r = __fdividef(inter, uni);
                    float iou = (uni > 0.0f) ? r : 0.0f;
                    acc[t] += iou * q.y;
                }
            }
        }
    }

    #pragma unroll
    for (int t = 0; t < TBOX; t++) {
        int b = box0 + t * 256;
        if (b < N) partial[(size_t)k * N + b] = acc[t] * Pv[t];
    }
}

// ---------------- K3: reduce over keys + argmax ----------------------------
__global__ __launch_bounds__(256) void reduce_kernel(
        const float* __restrict__ partial,
        const float* __restrict__ projW,
        float* __restrict__ out, int N) {
    int n = blockIdx.x * 256 + threadIdx.x;
    if (n >= N) return;
    float p[NCLS];
    #pragma unroll
    for (int c = 0; c < NCLS; c++) p[c] = 0.0f;
    #pragma unroll
    for (int cam = 0; cam < NCAM; cam++)
        #pragma unroll
        for (int c = 0; c < NCLS; c++)
            p[c] += partial[(size_t)(cam * NCLS + c) * N + n];
    float nv = 0.0f;
    #pragma unroll
    for (int cam = 0; cam < NCAM; cam++) nv += projW[(cam*6+5)*N + n];
    float denom = 1e-5f + nv;
    float best = -1e30f; int bk = 0;
    #pragma unroll
    for (int c = 0; c < NCLS; c++) {
        float v = p[c] / denom;
        if (v > best) { best = v; bk = c; }   // strict >: first-max (jnp.argmax)
    }
    out[n]     = (float)(bk + 1);
    out[N + n] = best;
}

extern "C" void kernel_launch(void* const* d_in, const int* in_sizes, int n_in,
                              void* d_out, int out_size, void* d_ws, size_t ws_size,
                              hipStream_t stream) {
    const float*  pred_boxes = (const float*)d_in[0];
    const float*  ia         = (const float*)d_in[1];
    const float*  la         = (const float*)d_in[2];
    const float*  l2i        = (const float*)d_in[3];
    const float4* det_boxes  = (const float4*)d_in[4];
    const int*    det_labels = (const int*)d_in[5];
    const float*  det_scores = (const float*)d_in[6];
    const int*    det_batch  = (const int*)d_in[7];
    const int*    det_cam    = (const int*)d_in[8];
    float* out = (float*)d_out;

    int N = in_sizes[0] / 7;   // 4096
    int M = in_sizes[4] / 4;   // 6144
    int PB = (N + 255) / 256;  // 16
    int BX = (N + 256*TBOX - 1) / (256*TBOX);  // 4
    int CAPW = (M + 3) / 4;    // worst-case per-wave bucket size

    // ws layout (16B-aligned slabs)
    char* w = (char*)d_ws;
    float* slab    = (float*)w;                               // 240*CAPW*8 floats
    size_t off = (size_t)NKEY * 4 * CAPW * 8 * 4;
    float* projW   = (float*)(w + off);                       // 36*N floats
    off += (size_t)36 * N * 4;
    float* partial = (float*)(w + off);                       // 60*N floats
    off += (size_t)NKEY * N * 4;
    int*   cnt     = (int*)(w + off);                         // 240 ints

    prep_kernel<<<PB + NKEY, 256, 0, stream>>>(pred_boxes, ia, la, l2i,
                                               det_boxes, det_labels, det_scores,
                                               det_batch, det_cam,
                                               projW, slab, cnt, N, M, PB, CAPW);
    main_kernel<<<dim3(BX, NKEY), 256, 0, stream>>>(projW, slab, cnt, partial, N, CAPW);
    reduce_kernel<<<PB, 256, 0, stream>>>(partial, projW, out, N);
}

// Round 9
// 119.652 us; speedup vs baseline: 2.1369x; 1.0024x over previous
//
#include <hip/hip_runtime.h>
#include <cstdint>
#include <climits>

#pragma clang fp contract(off)

#define NCAM 6
#define NCLS 10
#define NKEY 60          // cam*10+cls
#define IMGW 1600
#define IMGH 900
#define TBOX 4           // boxes per thread in main kernel
#define CHUNK 256        // dets staged per LDS pass
#define ZB 4             // zero-init blocks in prep

// XLA-style float->int32: saturate out-of-range, NaN -> 0. (Verified R3..R8.)
__device__ __forceinline__ int sat_f2i(float f) {
    if (f != f) return 0;
    if (f >= 2147483648.0f) return INT_MAX;
    if (f <= -2147483648.0f) return INT_MIN;
    return (int)f;
}

// ---------------- K1: prep = projection + bucketing + zero-init ------------
// blocks [0,PB): projection -> projW[36][N]
// blocks [PB,PB+60): bucket key k into 4 per-wave sub-slabs (ballot compact)
// blocks [PB+60, PB+60+ZB): zero probs[10][N]; first also zeroes tickets
__global__ __launch_bounds__(256) void prep_kernel(
        const float*  __restrict__ boxes,   // [N][7]
        const float*  __restrict__ ia,      // [6][4][4]
        const float*  __restrict__ la,      // [4][4]
        const float*  __restrict__ l2i,     // [6][4][4]
        const float4* __restrict__ det_boxes,
        const int*    __restrict__ det_labels,
        const float*  __restrict__ det_scores,
        const int*    __restrict__ det_batch,
        const int*    __restrict__ det_cam,
        float* __restrict__ projW,          // [36][N] comp-major
        float* __restrict__ slab,           // [60*4][CAPW][8]
        int*   __restrict__ cnt,            // [60*4]
        float* __restrict__ probs,          // [10][N]  (zeroed here)
        int*   __restrict__ ticket,         // [BX]     (zeroed here)
        int N, int M, int PB, int CAPW, int BX) {
    int tid = threadIdx.x;
    int bid = (int)blockIdx.x;

    if (bid >= PB + NKEY) {
        // ---- zero-init probs + tickets ----
        int zb = bid - (PB + NKEY);
        int ZT = NCLS * N;
        for (int i = zb * 256 + tid; i < ZT; i += ZB * 256) probs[i] = 0.0f;
        if (zb == 0 && tid < BX) ticket[tid] = 0;
        return;
    }

    if (bid < PB) {
        // ---- projection (validated R3..R8 math) ----
        int n = bid * 256 + tid;
        if (n >= N) return;
        float bx = boxes[n*7+0], by = boxes[n*7+1], bz = boxes[n*7+2];
        float dx = boxes[n*7+3], dy = boxes[n*7+4], dz = boxes[n*7+5];
        float yaw = boxes[n*7+6];
        float c = (float)cos((double)yaw);
        float s = (float)sin((double)yaw);

        float a00=la[0],a01=la[1],a02=la[2],t0=la[3];
        float a10=la[4],a11=la[5],a12=la[6],t1=la[7];
        float a20=la[8],a21=la[9],a22=la[10],t2=la[11];
        float det = a00*(a11*a22-a12*a21) - a01*(a10*a22-a12*a20) + a02*(a10*a21-a11*a20);
        float id = 1.0f/det;
        float r00=(a11*a22-a12*a21)*id, r01=(a02*a21-a01*a22)*id, r02=(a01*a12-a02*a11)*id;
        float r10=(a12*a20-a10*a22)*id, r11=(a00*a22-a02*a20)*id, r12=(a02*a10-a00*a12)*id;
        float r20=(a10*a21-a11*a20)*id, r21=(a01*a20-a00*a21)*id, r22=(a00*a11-a01*a10)*id;

        float PX[8], PY[8], PZ[8];
        #pragma unroll
        for (int k = 0; k < 8; k++) {
            float sx = ((k==0||k==1||k==4||k==5) ?  0.5f : -0.5f) * dx;
            float sy = ((k==0||k==3||k==4||k==7) ?  0.5f : -0.5f) * dy;
            float sz = ((k>=4)                   ?  0.5f : -0.5f) * dz;
            float cx = sx*c - sy*s + bx;
            float cy = sx*s + sy*c + by;
            float cz = sz + bz;
            float ux = cx - t0, uy = cy - t1, uz = cz - t2;
            PX[k] = r00*ux + r01*uy + r02*uz;
            PY[k] = r10*ux + r11*uy + r12*uz;
            PZ[k] = r20*ux + r21*uy + r22*uz;
        }
        for (int cam = 0; cam < NCAM; cam++) {
            const float* L = l2i + cam*16;
            const float* A = ia  + cam*16;
            int minx = INT_MAX, miny = INT_MAX, maxx = INT_MIN, maxy = INT_MIN;
            #pragma unroll
            for (int k = 0; k < 8; k++) {
                float u = L[0]*PX[k] + L[1]*PY[k] + L[2]*PZ[k]  + L[3];
                float v = L[4]*PX[k] + L[5]*PY[k] + L[6]*PZ[k]  + L[7];
                float w = L[8]*PX[k] + L[9]*PY[k] + L[10]*PZ[k] + L[11];
                float zc = fminf(fmaxf(w, 1e-5f), 100000.0f);
                float x = u / zc, y = v / zc;
                float xx = A[0]*x + A[1]*y + A[2]*zc + A[3];
                float yy = A[4]*x + A[5]*y + A[6]*zc + A[7];
                int pxi = sat_f2i(xx); pxi = min(max(pxi, 0), IMGW);
                int pyi = sat_f2i(yy); pyi = min(max(pyi, 0), IMGH);
                minx = min(minx, pxi); maxx = max(maxx, pxi);
                miny = min(miny, pyi); maxy = max(maxy, pyi);
            }
            float x1 = (float)minx, y1 = (float)miny, x2 = (float)maxx, y2 = (float)maxy;
            float validf = ((x2 - x1) > 0.0f && (y2 - y1) > 0.0f) ? 1.0f : 0.0f;
            projW[(cam*6+0)*N + n] = x1;
            projW[(cam*6+1)*N + n] = y1;
            projW[(cam*6+2)*N + n] = x2;
            projW[(cam*6+3)*N + n] = y2;
            projW[(cam*6+4)*N + n] = (x2 - x1) * (y2 - y1);
            projW[(cam*6+5)*N + n] = validf;
        }
        return;
    }

    // ---- bucketing key k: 4 waves, independent det ranges, ballot compact --
    int k = bid - PB;
    int cam = k / NCLS, cls = k % NCLS;
    int w = tid >> 6, lane = tid & 63;
    int per = (M + 3) >> 2;
    int m0 = w * per, m1 = min(m0 + per, M);
    float* base = slab + (size_t)(k * 4 + w) * CAPW * 8;
    int pos = 0;
    for (int c = m0; c < m1; c += 64) {
        int m = c + lane;
        bool pred = false;
        if (m < m1) {
            int dc = det_cam[m], db = det_batch[m], dl = det_labels[m] - 1;
            pred = (db == 0) && (dc == cam) && (dl == cls);
        }
        unsigned long long ball = __ballot(pred);
        if (pred) {
            int p = pos + __popcll(ball & ((1ull << lane) - 1ull));
            float4 b = det_boxes[m];
            float area = (b.z - b.x) * (b.w - b.y);
            float4* o = (float4*)(base + (size_t)p * 8);
            o[0] = b;
            o[1] = make_float4(area, det_scores[m], 0.0f, 0.0f);
        }
        pos += __popcll(ball);
    }
    if (lane == 0) cnt[k * 4 + w] = pos;
}

// ---------------- K2: main accumulation + fused argmax (atomic ticket) -----
// grid (BX=4, 60, 4). Block (bx,k,z): 1024 boxes (TBOX=4/thread) vs sub-slab
// z of key k (~102 dets). LDS-staged dets, broadcast reads, 4 IoUs/thread/det.
// Class sums -> atomicAdd into probs[cls][N]. Last block per bx (ticket==239)
// reads probs (device-scope) and writes labels+scores.
__global__ __launch_bounds__(256) void main_kernel(
        const float* __restrict__ projW,
        const float* __restrict__ slab,
        const int*   __restrict__ cnt,
        float*       __restrict__ probs,    // [10][N]
        int*         __restrict__ ticket,   // [BX]
        float*       __restrict__ out,      // [2*N]
        int N, int CAPW) {
    #pragma clang fp contract(fast)          // IoU loop may fuse (validated R8)
    int tid = threadIdx.x;
    int k = blockIdx.y;
    int z = blockIdx.z;
    int cam = k / NCLS, cls = k % NCLS;
    int bx = blockIdx.x;
    int box0 = bx * (256 * TBOX) + tid;

    __shared__ float4 sbox[CHUNK];
    __shared__ float2 sq[CHUNK];
    __shared__ int is_last;

    float Px1[TBOX], Py1[TBOX], Px2[TBOX], Py2[TBOX], Pa[TBOX], Pv[TBOX], acc[TBOX];
    #pragma unroll
    for (int t = 0; t < TBOX; t++) {
        int b = box0 + t * 256;
        int bi = min(b, N - 1);              // loads valid; stores guarded
        Px1[t] = projW[(cam*6+0)*N + bi];
        Py1[t] = projW[(cam*6+1)*N + bi];
        Px2[t] = projW[(cam*6+2)*N + bi];
        Py2[t] = projW[(cam*6+3)*N + bi];
        Pa[t]  = projW[(cam*6+4)*N + bi];
        Pv[t]  = projW[(cam*6+5)*N + bi];
        acc[t] = 0.0f;
    }

    int nk = cnt[k * 4 + z];                 // block-uniform
    const float4* gb = (const float4*)(slab + (size_t)(k * 4 + z) * CAPW * 8);
    for (int base = 0; base < nk; base += CHUNK) {
        int cc = min(CHUNK, nk - base);
        __syncthreads();
        for (int i = tid; i < cc; i += 256) {
            float4 b0 = gb[(size_t)(base + i) * 2];
            float4 b1 = gb[(size_t)(base + i) * 2 + 1];
            sbox[i] = b0;
            sq[i] = make_float2(b1.x, b1.y);
        }
        __syncthreads();
        for (int m = 0; m < cc; m++) {
            float4 b = sbox[m];
            float2 q = sq[m];
            #pragma unroll
            for (int t = 0; t < TBOX; t++) {
                float ltx = fmaxf(b.x, Px1[t]);
                float lty = fmaxf(b.y, Py1[t]);
                float rbx = fminf(b.z, Px2[t]);
                float rby = fminf(b.w, Py2[t]);
                float iw = fmaxf(rbx - ltx, 0.0f);
                float ih = fmaxf(rby - lty, 0.0f);
                float inter = iw * ih;
                float uni = (q.x + Pa[t]) - inter;
                float r = __fdividef(inter, uni);
                float iou = (uni > 0.0f) ? r : 0.0f;
                acc[t] += iou * q.y;
            }
        }
    }

    #pragma unroll
    for (int t = 0; t < TBOX; t++) {
        int b = box0 + t * 256;
        float v = acc[t] * Pv[t];
        if (b < N && v != 0.0f) atomicAdd(&probs[(size_t)cls * N + b], v);
    }

    // ---- ticket: last of the 240 blocks for this bx does the epilogue ----
    __syncthreads();                         // all atomics issued & drained
    if (tid == 0) {
        __threadfence();                     // release
        int old = atomicAdd(&ticket[bx], 1);
        is_last = (old == NKEY * 4 - 1) ? 1 : 0;
    }
    __syncthreads();
    if (!is_last) return;
    __threadfence();                         // acquire

    #pragma unroll
    for (int t = 0; t < TBOX; t++) {
        int b = box0 + t * 256;
        if (b >= N) continue;
        float nv = 0.0f;
        #pragma unroll
        for (int c2 = 0; c2 < NCAM; c2++) nv += projW[(c2*6+5)*N + b];
        float denom = 1e-5f + nv;
        float best = -1e30f; int bk = 0;
        #pragma unroll
        for (int c2 = 0; c2 < NCLS; c2++) {
            float p = __hip_atomic_load(&probs[(size_t)c2 * N + b],
                                        __ATOMIC_RELAXED, __HIP_MEMORY_SCOPE_AGENT);
            float v = p / denom;
            if (v > best) { best = v; bk = c2; }   // strict >: first-max
        }
        out[b]     = (float)(bk + 1);
        out[N + b] = best;
    }
}

extern "C" void kernel_launch(void* const* d_in, const int* in_sizes, int n_in,
                              void* d_out, int out_size, void* d_ws, size_t ws_size,
                              hipStream_t stream) {
    const float*  pred_boxes = (const float*)d_in[0];
    const float*  ia         = (const float*)d_in[1];
    const float*  la         = (const float*)d_in[2];
    const float*  l2i        = (const float*)d_in[3];
    const float4* det_boxes  = (const float4*)d_in[4];
    const int*    det_labels = (const int*)d_in[5];
    const float*  det_scores = (const float*)d_in[6];
    const int*    det_batch  = (const int*)d_in[7];
    const int*    det_cam    = (const int*)d_in[8];
    float* out = (float*)d_out;

    int N = in_sizes[0] / 7;   // 4096
    int M = in_sizes[4] / 4;   // 6144
    int PB = (N + 255) / 256;  // 16
    int BX = (N + 256*TBOX - 1) / (256*TBOX);  // 4
    int CAPW = (M + 3) / 4;    // worst-case per-wave bucket size

    // ws layout (16B-aligned slabs)
    char* w = (char*)d_ws;
    float* slab   = (float*)w;                                // 240*CAPW*8 floats
    size_t off = (size_t)NKEY * 4 * CAPW * 8 * 4;
    float* projW  = (float*)(w + off);                        // 36*N floats
    off += (size_t)36 * N * 4;
    float* probs  = (float*)(w + off);                        // 10*N floats
    off += (size_t)NCLS * N * 4;
    int*   cnt    = (int*)(w + off);                          // 240 ints
    off += 256 * 4;
    int*   ticket = (int*)(w + off);                          // BX ints

    prep_kernel<<<PB + NKEY + ZB, 256, 0, stream>>>(
        pred_boxes, ia, la, l2i, det_boxes, det_labels, det_scores,
        det_batch, det_cam, projW, slab, cnt, probs, ticket, N, M, PB, CAPW, BX);
    main_kernel<<<dim3(BX, NKEY, 4), 256, 0, stream>>>(
        projW, slab, cnt, probs, ticket, out, N, CAPW);
}